// Round 1
// 156.892 us; speedup vs baseline: 1.0205x; 1.0205x over previous
//
#include <hip/hip_runtime.h>

#define NB 8
#define NC 128
#define NM 4096
#define FRAG 512   // shorts per (tile,ks) fragment block: 64 lanes x 8

typedef __attribute__((ext_vector_type(8))) short short8;
typedef __attribute__((ext_vector_type(4))) float floatx4;

#define MFMA(a, b, c) __builtin_amdgcn_mfma_f32_16x16x32_bf16(a, b, c, 0, 0, 0)
#define EXP2F(x) __builtin_amdgcn_exp2f(x)

union S8U { short8 v; uint2 u2[2]; };

__device__ __forceinline__ unsigned pack2bf(float a, float b) {
    unsigned ua = __float_as_uint(a);
    unsigned ub = __float_as_uint(b);
    ua += 0x7fffu + ((ua >> 16) & 1u);
    ub += 0x7fffu + ((ub >> 16) & 1u);
    return (ua >> 16) | (ub & 0xffff0000u);
}

// Single-instruction packed f32->bf16 (RNE), same rounding as pack2bf.
__device__ __forceinline__ unsigned cvt_pk_bf16(float a, float b) {
    unsigned r;
    asm("v_cvt_pk_bf16_f32 %0, %1, %2" : "=v"(r) : "v"(a), "v"(b));
    return r;
}

// QK softmax scale folded into fX: sqrt(2^-3.5 * log2(e)); RS = 1/SF.
__constant__ float SF_C = 0.35712442f;
__constant__ float RS_C = 2.8001530f;

// ---------------------------------------------------------------------------
// Fragment-order layouts (one contiguous 1024B chunk per wave fragment load):
//   fX[b][mt(256)][ks(4)][lane(64)][8] : lane l=(lq*16+lm) holds
//       f-row (mt*16+lm), cols ks*32+lq*8..+7, scaled by SF, bf16.
//   gX[b][nblk(32)][ot(8)][k2(4)][lane(64)][8] : lane l holds
//       g-row o=ot*16+lm, cols n=nblk*128+k2*32+lq*8..+7, bf16.
// ---------------------------------------------------------------------------

// P1: fX from f (transpose + scale + bf16 + fragment order)
__global__ __launch_bounds__(256) void k_prep_f(
    const float* __restrict__ f, unsigned short* __restrict__ fX)
{
    __shared__ float Ls[128][65];
    const int tid = threadIdx.x;
    const int b   = blockIdx.x & 7;
    const int m0  = (blockIdx.x >> 3) * 64;
    const float* fb = f + (size_t)b * NC * NM;
    #pragma unroll
    for (int k = 0; k < 32; ++k) {
        int idx = tid + k * 256;
        int c = idx >> 6, mm = idx & 63;
        Ls[c][mm] = fb[(size_t)c * NM + m0 + mm];
    }
    __syncthreads();
    const float sf = SF_C;
    const int m  = tid >> 2;
    const int ks = tid & 3;
    const int ch = ks * 32;
    unsigned pk[16];
    #pragma unroll
    for (int i = 0; i < 16; ++i)
        pk[i] = pack2bf(Ls[ch + 2 * i][m] * sf, Ls[ch + 2 * i + 1][m] * sf);
    const int Mg  = m0 + m;
    const int mt  = Mg >> 4;
    const int lmm = Mg & 15;
    unsigned short* dst = fX + ((size_t)b * 256 + mt) * 4 * FRAG + ks * FRAG;
    #pragma unroll
    for (int q = 0; q < 4; ++q)
        *(uint4*)(dst + (q * 16 + lmm) * 8) =
            make_uint4(pk[4 * q], pk[4 * q + 1], pk[4 * q + 2], pk[4 * q + 3]);
}

// ---------------------------------------------------------------------------
// P2 (MFMA): gX = bf16( (w1a*RS) . fX ) in fragment order.
// grid 256 = b(8) x nblk(32); 4 waves; wave wv owns ot = 2wv, 2wv+1.
// ---------------------------------------------------------------------------
__global__ __launch_bounds__(256) void k_prep_g(
    const unsigned short* __restrict__ fX, const float* __restrict__ w1,
    unsigned short* __restrict__ gX)
{
    __shared__ unsigned short gt[128][136];   // [o][n-local]
    const int tid = threadIdx.x;
    const int wv  = tid >> 6;
    const int l   = tid & 63;
    const int lm  = l & 15;
    const int lq  = l >> 4;
    const int b    = blockIdx.x & 7;
    const int nblk = blockIdx.x >> 3;

    const float rs = RS_C;

    short8 wf2[2][4];
    #pragma unroll
    for (int j = 0; j < 2; ++j) {
        const int o = (wv * 2 + j) * 16 + lm;
        #pragma unroll
        for (int ks = 0; ks < 4; ++ks) {
            const float* wp = w1 + (size_t)o * (2 * NC) + ks * 32 + lq * 8;
            S8U t;
            t.u2[0] = make_uint2(pack2bf(wp[0] * rs, wp[1] * rs),
                                 pack2bf(wp[2] * rs, wp[3] * rs));
            t.u2[1] = make_uint2(pack2bf(wp[4] * rs, wp[5] * rs),
                                 pack2bf(wp[6] * rs, wp[7] * rs));
            wf2[j][ks] = t.v;
        }
    }

    const unsigned short* fXb = fX + (size_t)b * NM * NC;
    #pragma unroll 2
    for (int nt = 0; nt < 8; ++nt) {
        short8 af[4];
        #pragma unroll
        for (int ks = 0; ks < 4; ++ks)
            af[ks] = *(const short8*)
                (fXb + (size_t)(nblk * 8 + nt) * 4 * FRAG + ks * FRAG + l * 8);
        #pragma unroll
        for (int j = 0; j < 2; ++j) {
            floatx4 D = {0.f, 0.f, 0.f, 0.f};
            #pragma unroll
            for (int ks = 0; ks < 4; ++ks)
                D = MFMA(af[ks], wf2[j][ks], D);
            *(uint2*)&gt[(wv * 2 + j) * 16 + lm][nt * 16 + lq * 4] =
                make_uint2(pack2bf(D[0], D[1]), pack2bf(D[2], D[3]));
        }
    }
    __syncthreads();

    #pragma unroll
    for (int j = 0; j < 2; ++j) {
        const int ot = wv * 2 + j;
        #pragma unroll
        for (int k2 = 0; k2 < 4; ++k2) {
            uint4 v = *(const uint4*)&gt[ot * 16 + lm][k2 * 32 + lq * 8];
            *(uint4*)(gX + (((size_t)b * 32 + nblk) * 8 + ot) * 4 * FRAG
                      + k2 * FRAG + l * 8) = v;
        }
    }
}

// ---------------------------------------------------------------------------
// Main: MFMA flash attention + fused cls head, TN=128/iter, fragment-order
// K/G loads; l in fp32 VALU from the exp2 registers feeding Ps.
// Ps is stored in FRAGMENT ORDER per buf: [mt(4)][k2(4)][slot(64)][8 bf16]
// with a bits[5:4]^=bits[8:7] XOR swizzle (per-lane constant). PV-side
// ds_read_b128 is lane-linear (conflict-free); QK-side b64 writes spread
// their 4-lane groups across distinct bank pairs.
// grid 512 = b(8) x mblock(64, 64 m); 4 waves, 2 blocks/CU.
// ---------------------------------------------------------------------------
__global__ __launch_bounds__(256, 2) void k_attn(
    const unsigned short* __restrict__ fX,
    const unsigned short* __restrict__ gX,
    const float* __restrict__ w1,
    const float* __restrict__ b1v, const float* __restrict__ gammav,
    const float* __restrict__ betav, const float* __restrict__ rmeanv,
    const float* __restrict__ rvarv, const float* __restrict__ w2v,
    const float* __restrict__ b2v, float* __restrict__ out)
{
    __shared__ __align__(16) char Ps[2][16384];
    __shared__ float lpart[4][64];
    __shared__ float opart[4][64];

    const int tid = threadIdx.x;
    const int w   = tid >> 6;
    const int l   = tid & 63;
    const int lm  = l & 15;
    const int lq  = l >> 4;
    const int b   = blockIdx.x & 7;
    const int m0  = (blockIdx.x >> 3) * 64;

    // --- Ps addressing (fragment order + XOR swizzle), per-lane constant ---
    // QK output: lane holds S[n = w*16 + lq*4 + r][m = lm] (A half) and
    // n+64 (B half). Fragment slot for n: k2 = n>>5, slotq = (n&31)>>3,
    // elem = n&7; slot = slotq*16 + lm.
    const int lq0 = lq & 1;
    const int lq1 = lq >> 1;
    const int lm3 = lm >> 3;
    const unsigned Xsw = (unsigned)(((lq1 << 1) | lm3) << 4);
    // A half: k2 = w>>1, slotq = 2*(w&1) + lq1, elem base = 4*lq0.
    const unsigned wofsA =
        ((((unsigned)(w >> 1) * 4 * 16) + ((unsigned)(2 * (w & 1) + lq1) * 16)
          + (unsigned)lm) * 16 + (unsigned)(8 * lq0)) ^ Xsw;
    // B half: n += 64 -> k2 += 2 -> +2048 bytes (disjoint from XOR bits).
    // PV read: lane-linear 16B slots, same swizzle on slot index.
    const unsigned rofs = ((unsigned)l * 16) ^ ((((unsigned)l >> 3) & 3u) << 4);

    const unsigned short* fXb = fX + (size_t)b * NM * NC;
    const unsigned short* gXb = gX + (size_t)b * NC * NM;

    short8 qf[4][4];
    {
        const int qt0 = m0 >> 4;
        #pragma unroll
        for (int mt = 0; mt < 4; ++mt)
            #pragma unroll
            for (int ks = 0; ks < 4; ++ks)
                qf[mt][ks] = *(const short8*)
                    (fXb + (size_t)(qt0 + mt) * 4 * FRAG + ks * FRAG + l * 8);
    }

    const unsigned short* kpA = fXb + (size_t)w * 4 * FRAG + l * 8;
    const unsigned short* kpB = fXb + (size_t)(4 + w) * 4 * FRAG + l * 8;
    const unsigned short* gp0 = gXb + (size_t)(2 * w) * 4 * FRAG + l * 8;
    const unsigned short* gp1 = gXb + (size_t)(2 * w + 1) * 4 * FRAG + l * 8;

    short8 kfA[4], kfB[4], gf0[4], gf1[4];
    #pragma unroll
    for (int ks = 0; ks < 4; ++ks) {
        kfA[ks] = *(const short8*)(kpA + ks * FRAG);
        kfB[ks] = *(const short8*)(kpB + ks * FRAG);
    }
    #pragma unroll
    for (int k2 = 0; k2 < 4; ++k2) {
        gf0[k2] = *(const short8*)(gp0 + k2 * FRAG);
        gf1[k2] = *(const short8*)(gp1 + k2 * FRAG);
    }

    floatx4 u[4][2];
    float lsum[4] = {0.f, 0.f, 0.f, 0.f};
    #pragma unroll
    for (int mt = 0; mt < 4; ++mt) {
        u[mt][0] = (floatx4){0.f, 0.f, 0.f, 0.f};
        u[mt][1] = (floatx4){0.f, 0.f, 0.f, 0.f};
    }

    for (int it = 0; it < 32; ++it) {
        const int buf = it & 1;
        char* psb = Ps[buf];

        floatx4 svA[4], svB[4];
        __builtin_amdgcn_s_setprio(1);
        #pragma unroll
        for (int mt = 0; mt < 4; ++mt) {
            floatx4 a = {-24.f, -24.f, -24.f, -24.f};
            floatx4 bb = {-24.f, -24.f, -24.f, -24.f};
            #pragma unroll
            for (int ks = 0; ks < 4; ++ks) {
                a  = MFMA(kfA[ks], qf[mt][ks], a);
                bb = MFMA(kfB[ks], qf[mt][ks], bb);
            }
            svA[mt] = a; svB[mt] = bb;
        }
        __builtin_amdgcn_s_setprio(0);
        {
            const int kstep = (it < 31) ? 8 * 4 * FRAG : 0;
            kpA += kstep; kpB += kstep;
            #pragma unroll
            for (int ks = 0; ks < 4; ++ks) {
                kfA[ks] = *(const short8*)(kpA + ks * FRAG);
                kfB[ks] = *(const short8*)(kpB + ks * FRAG);
            }
        }

        #pragma unroll
        for (int mt = 0; mt < 4; ++mt) {
            float pA0 = EXP2F(svA[mt][0]);
            float pA1 = EXP2F(svA[mt][1]);
            float pA2 = EXP2F(svA[mt][2]);
            float pA3 = EXP2F(svA[mt][3]);
            float pB0 = EXP2F(svB[mt][0]);
            float pB1 = EXP2F(svB[mt][1]);
            float pB2 = EXP2F(svB[mt][2]);
            float pB3 = EXP2F(svB[mt][3]);
            lsum[mt] += ((pA0 + pA1) + (pA2 + pA3)) +
                        ((pB0 + pB1) + (pB2 + pB3));
            *(uint2*)(psb + mt * 4096 + wofsA) =
                make_uint2(cvt_pk_bf16(pA0, pA1), cvt_pk_bf16(pA2, pA3));
            *(uint2*)(psb + mt * 4096 + wofsA + 2048) =
                make_uint2(cvt_pk_bf16(pB0, pB1), cvt_pk_bf16(pB2, pB3));
        }
        __syncthreads();

        #pragma unroll
        for (int k2 = 0; k2 < 4; ++k2) {
            short8 pf[4];
            #pragma unroll
            for (int mt = 0; mt < 4; ++mt)
                pf[mt] = *(const short8*)(psb + mt * 4096 + k2 * 1024 + rofs);
            __builtin_amdgcn_s_setprio(1);
            #pragma unroll
            for (int mt = 0; mt < 4; ++mt) {
                u[mt][0] = MFMA(pf[mt], gf0[k2], u[mt][0]);
                u[mt][1] = MFMA(pf[mt], gf1[k2], u[mt][1]);
            }
            __builtin_amdgcn_s_setprio(0);
        }
        {
            const int gstep = (it < 31) ? 8 * 4 * FRAG : 0;
            gp0 += gstep; gp1 += gstep;
            #pragma unroll
            for (int k2 = 0; k2 < 4; ++k2) {
                gf0[k2] = *(const short8*)(gp0 + k2 * FRAG);
                gf1[k2] = *(const short8*)(gp1 + k2 * FRAG);
            }
        }
    }

    #pragma unroll
    for (int mt = 0; mt < 4; ++mt) {
        lsum[mt] += __shfl_xor(lsum[mt], 16);
        lsum[mt] += __shfl_xor(lsum[mt], 32);
    }
    if (lq == 0) {
        #pragma unroll
        for (int mt = 0; mt < 4; ++mt)
            lpart[w][mt * 16 + lm] = lsum[mt];
    }

    floatx4 hacc[4][2];
    {
        const float rs = RS_C;
        #pragma unroll
        for (int j = 0; j < 2; ++j) {
            int o = w * 32 + j * 16 + lm;
            short8 wf[4];
            #pragma unroll
            for (int ks = 0; ks < 4; ++ks) {
                const float* wp = w1 + (size_t)o * (2 * NC) + NC + ks * 32 + lq * 8;
                S8U t;
                t.u2[0] = make_uint2(pack2bf(wp[0] * rs, wp[1] * rs),
                                     pack2bf(wp[2] * rs, wp[3] * rs));
                t.u2[1] = make_uint2(pack2bf(wp[4] * rs, wp[5] * rs),
                                     pack2bf(wp[6] * rs, wp[7] * rs));
                wf[ks] = t.v;
            }
            #pragma unroll
            for (int mt = 0; mt < 4; ++mt) {
                floatx4 a = {0.f, 0.f, 0.f, 0.f};
                #pragma unroll
                for (int ks = 0; ks < 4; ++ks)
                    a = MFMA(qf[mt][ks], wf[ks], a);
                hacc[mt][j] = a;
            }
        }
    }
    __syncthreads();

    float Abn[2], Dbn[2], W2[2];
    #pragma unroll
    for (int j = 0; j < 2; ++j) {
        int o = w * 32 + j * 16 + lm;
        float Ar = gammav[o] * rsqrtf(rvarv[o] + 1e-5f);
        Abn[j] = Ar;
        Dbn[j] = (b1v[o] - rmeanv[o]) * Ar + betav[o];
        W2[j]  = w2v[o];
    }
    float av[16];
    #pragma unroll
    for (int mt = 0; mt < 4; ++mt) {
        float4 L0 = *(const float4*)&lpart[0][mt * 16 + lq * 4];
        float4 L1 = *(const float4*)&lpart[1][mt * 16 + lq * 4];
        float4 L2 = *(const float4*)&lpart[2][mt * 16 + lq * 4];
        float4 L3 = *(const float4*)&lpart[3][mt * 16 + lq * 4];
        float4 Lt;
        Lt.x = (L0.x + L1.x) + (L2.x + L3.x);
        Lt.y = (L0.y + L1.y) + (L2.y + L3.y);
        Lt.z = (L0.z + L1.z) + (L2.z + L3.z);
        Lt.w = (L0.w + L1.w) + (L2.w + L3.w);
        #pragma unroll
        for (int r = 0; r < 4; ++r) {
            float rl = 1.f / ((const float*)&Lt)[r];
            float t0 = Abn[0] * (u[mt][0][r] * rl + hacc[mt][0][r]) + Dbn[0];
            float t1 = Abn[1] * (u[mt][1][r] * rl + hacc[mt][1][r]) + Dbn[1];
            t0 = t0 >= 0.f ? t0 : 0.01f * t0;
            t1 = t1 >= 0.f ? t1 : 0.01f * t1;
            av[mt * 4 + r] = W2[0] * t0 + W2[1] * t1;
        }
    }
    #pragma unroll
    for (int i = 0; i < 16; ++i) {
        av[i] += __shfl_xor(av[i], 1);
        av[i] += __shfl_xor(av[i], 2);
        av[i] += __shfl_xor(av[i], 4);
        av[i] += __shfl_xor(av[i], 8);
    }
    if (lm == 0) {
        #pragma unroll
        for (int mt = 0; mt < 4; ++mt)
            #pragma unroll
            for (int r = 0; r < 4; ++r)
                opart[w][mt * 16 + lq * 4 + r] = av[mt * 4 + r];
    }
    __syncthreads();
    if (tid < 64)
        out[(size_t)b * NM + m0 + tid] =
            b2v[0] + opart[0][tid] + opart[1][tid] + opart[2][tid] + opart[3][tid];
}

extern "C" void kernel_launch(void* const* d_in, const int* in_sizes, int n_in,
                              void* d_out, int out_size, void* d_ws, size_t ws_size,
                              hipStream_t stream) {
    const float* f     = (const float*)d_in[0];
    const float* w1    = (const float*)d_in[1];
    const float* b1    = (const float*)d_in[2];
    const float* gamma = (const float*)d_in[3];
    const float* beta  = (const float*)d_in[4];
    const float* rmean = (const float*)d_in[5];
    const float* rvar  = (const float*)d_in[6];
    const float* w2    = (const float*)d_in[7];
    const float* b2    = (const float*)d_in[8];
    float* out = (float*)d_out;

    unsigned short* fX = (unsigned short*)d_ws;              // 8 MB bf16 frag-order
    unsigned short* gX = fX + (size_t)NB * NM * NC;          // 8 MB bf16 frag-order

    hipLaunchKernelGGL(k_prep_f, dim3(512), dim3(256), 0, stream, f, fX);
    hipLaunchKernelGGL(k_prep_g, dim3(256), dim3(256), 0, stream, fX, w1, gX);
    hipLaunchKernelGGL(k_attn,   dim3(512), dim3(256), 0, stream,
                       fX, gX, w1, b1, gamma, beta, rmean, rvar, w2, b2, out);
}